// Round 1
// baseline (560.627 us; speedup 1.0000x reference)
//
#include <hip/hip_runtime.h>
#include <cmath>

// Problem geometry (fixed by reference setup_inputs):
//   x : (16,1,1024,1024) f32, y : same, mask : (1024,1024) f32, out: 1 f32
#define IMG_W   1024
#define IMG_H   1024
#define NIMG    16
#define HW      (1024 * 1024)          // 2^20
#define NHW     (16 * 1024 * 1024)     // 2^24
#define WPR     16                     // 64-bit words per row (1024/64)
#define WPI     (IMG_H * WPR)          // words per image = 16384

struct GW { float w[9]; };             // gaussian taps, w[|d|], d in [-8,8]

// ---------------------------------------------------------------- blur ----
__global__ void blur_v(const float* __restrict__ in, float* __restrict__ out, GW g) {
    int gid = blockIdx.x * 256 + threadIdx.x;          // over NHW
    int x = gid & 1023;
    int y = (gid >> 10) & 1023;
    const float* img = in + (size_t)(gid >> 20) * HW;
    float s = 0.f;
#pragma unroll
    for (int k = -8; k <= 8; ++k) {
        int yy = y + k;
        yy = yy < 0 ? -yy : (yy > 1023 ? 2046 - yy : yy);   // reflect-101
        s += g.w[k < 0 ? -k : k] * img[yy * IMG_W + x];
    }
    out[gid] = s;
}

__global__ void blur_h(const float* __restrict__ in, float* __restrict__ out, GW g) {
    int gid = blockIdx.x * 256 + threadIdx.x;
    int x = gid & 1023;
    int y = (gid >> 10) & 1023;
    const float* img = in + (size_t)(gid >> 20) * HW;
    float s = 0.f;
#pragma unroll
    for (int k = -8; k <= 8; ++k) {
        int xx = x + k;
        xx = xx < 0 ? -xx : (xx > 1023 ? 2046 - xx : xx);
        s += g.w[k < 0 ? -k : k] * img[y * IMG_W + xx];
    }
    out[gid] = s;
}

// ------------------------------------------------------- sobel + bins ----
__global__ void grad_mag(const float* __restrict__ sm, float* __restrict__ mag,
                         unsigned char* __restrict__ bin) {
    int gid = blockIdx.x * 256 + threadIdx.x;
    int x = gid & 1023;
    int y = (gid >> 10) & 1023;
    const float* img = sm + (size_t)(gid >> 20) * HW;
    int xm = (x == 0) ? 1 : x - 1,   xp = (x == 1023) ? 1022 : x + 1;   // reflect-101
    int ym = (y == 0) ? 1 : y - 1,   yp = (y == 1023) ? 1022 : y + 1;
    float a00 = img[ym * IMG_W + xm], a01 = img[ym * IMG_W + x], a02 = img[ym * IMG_W + xp];
    float a10 = img[y  * IMG_W + xm],                             a12 = img[y  * IMG_W + xp];
    float a20 = img[yp * IMG_W + xm], a21 = img[yp * IMG_W + x], a22 = img[yp * IMG_W + xp];
    // XLA conv is cross-correlation: gx = right-left, gy = bottom-top
    float gx = (a02 - a00) + 2.f * (a12 - a10) + (a22 - a20);
    float gy = (a20 - a00) + 2.f * (a21 - a01) + (a22 - a02);
    float m  = sqrtf(gx * gx + gy * gy);
    // angle bin: 0 = E/W, 1 = 45deg, 2 = N/S, 3 = 135deg
    const float T1 = 0.41421356237309503f;  // tan(22.5)
    const float T2 = 2.41421356237309510f;  // tan(67.5)
    float ax = fabsf(gx), ay = fabsf(gy);
    int b;
    if (ay < T1 * ax)      b = 0;
    else if (ay > T2 * ax) b = 2;
    else                   b = ((gx > 0.f) == (gy > 0.f)) ? 1 : 3;
    mag[gid] = m;
    bin[gid] = (unsigned char)b;
}

// ----------------------------------------------- NMS + thresholds (bit) ----
__global__ void nms_pack(const float* __restrict__ mag, const unsigned char* __restrict__ bin,
                         unsigned long long* __restrict__ strongw,
                         unsigned long long* __restrict__ weakw) {
    int gid = blockIdx.x * 256 + threadIdx.x;
    int x = gid & 1023;
    int y = (gid >> 10) & 1023;
    const float* m = mag + (size_t)(gid >> 20) * HW;
    float c = m[y * IMG_W + x];
    int b = bin[gid];
    const int d1y[4] = {0, -1, -1, -1};
    const int d1x[4] = {1,  1,  0, -1};
    int y1 = y + d1y[b], x1 = x + d1x[b];
    int y2 = y - d1y[b], x2 = x - d1x[b];
    // zero-padded neighbors (reference pads mag with 0 for NMS)
    float n1 = (y1 >= 0 && y1 < IMG_H && x1 >= 0 && x1 < IMG_W) ? m[y1 * IMG_W + x1] : 0.f;
    float n2 = (y2 >= 0 && y2 < IMG_H && x2 >= 0 && x2 < IMG_W) ? m[y2 * IMG_W + x2] : 0.f;
    bool keep   = (c >= n1) && (c >= n2);
    bool strong = keep && (c > 0.2f);
    bool weak   = keep && (c > 0.1f);
    unsigned long long sb = __ballot(strong);
    unsigned long long wb = __ballot(weak);
    if ((threadIdx.x & 63) == 0) {
        strongw[gid >> 6] = sb;
        weakw[gid >> 6]   = wb;
    }
}

// ------------------------------------------------------------ hysteresis ----
// One workgroup per image. Strong bits (128KB) in LDS; monotone in-place
// Gauss-Seidel dilation sweeps until fixpoint (== reference's while_loop
// fixpoint; convergence for this data is far below the 256-iter cap).
__global__ void __launch_bounds__(1024, 1)
hyst(unsigned long long* __restrict__ strongw, const unsigned long long* __restrict__ weakw) {
    __shared__ unsigned long long S[WPI];   // [1024 rows][16 words] = 128 KiB
    __shared__ int chg;
    unsigned long long* sg = strongw + (size_t)blockIdx.x * WPI;
    const unsigned long long* wk = weakw + (size_t)blockIdx.x * WPI;
    int t  = threadIdx.x;        // 0..1023
    int c  = t & 15;             // word column
    int r0 = (t >> 4) * 16;      // first of 16 owned rows

    for (int i = 0; i < 16; ++i) S[(r0 + i) * WPR + c] = sg[(r0 + i) * WPR + c];
    __syncthreads();

    for (int pass = 0; pass < 4096; ++pass) {
        if (t == 0) chg = 0;
        __syncthreads();
        int any = 0;
        for (int i = 0; i < 16; ++i) {
            int r = (pass & 1) ? (r0 + 15 - i) : (r0 + i);   // zigzag sweeps
            unsigned long long w  = S[r * WPR + c];
            unsigned long long ww = wk[r * WPR + c];
            if (!(ww & ~w)) continue;                         // nothing can grow here
            unsigned long long up = 0, dn = 0, upl = 0, upr = 0, dnl = 0, dnr = 0, ml = 0, mr = 0;
            if (r > 0)    { up = S[(r - 1) * WPR + c];
                            if (c > 0)  upl = S[(r - 1) * WPR + c - 1];
                            if (c < 15) upr = S[(r - 1) * WPR + c + 1]; }
            if (r < 1023) { dn = S[(r + 1) * WPR + c];
                            if (c > 0)  dnl = S[(r + 1) * WPR + c - 1];
                            if (c < 15) dnr = S[(r + 1) * WPR + c + 1]; }
            if (c > 0)  ml = S[r * WPR + c - 1];
            if (c < 15) mr = S[r * WPR + c + 1];
            unsigned long long H =
                  up | (up << 1) | (up >> 1) | (upl >> 63) | (upr << 63)
                | w  | (w  << 1) | (w  >> 1) | (ml  >> 63) | (mr  << 63)
                | dn | (dn << 1) | (dn >> 1) | (dnl >> 63) | (dnr << 63);
            unsigned long long nw = w | (H & ww);
            // in-word horizontal flood through weak runs
            for (;;) {
                unsigned long long nn = nw | (((nw << 1) | (nw >> 1)) & ww);
                if (nn == nw) break;
                nw = nn;
            }
            if (nw != w) { S[r * WPR + c] = nw; any = 1; }
        }
        if (any) chg = 1;
        __syncthreads();
        int done = (chg == 0);
        __syncthreads();          // protect chg read from next pass's reset
        if (done) break;
    }

    for (int i = 0; i < 16; ++i) sg[(r0 + i) * WPR + c] = S[(r0 + i) * WPR + c];
}

// ------------------------------------------------------------------ loss ----
__global__ void zero_acc(double* acc) { *acc = 0.0; }

__global__ void loss_k(const unsigned long long* __restrict__ strongw,
                       const float* __restrict__ y, const float* __restrict__ mask,
                       double* __restrict__ acc) {
    int stride = gridDim.x * 256;
    float local = 0.f;
    for (int gid = blockIdx.x * 256 + threadIdx.x; gid < NHW; gid += stride) {
        int x  = gid & 1023;
        int yy = (gid >> 10) & 1023;
        float m  = mask[yy * IMG_W + x];
        float yv = y[gid];
        float e  = (float)((strongw[gid >> 6] >> (gid & 63)) & 1ull);
        local += fabsf(e * m - yv * m);
    }
    for (int off = 32; off; off >>= 1) local += __shfl_down(local, off);
    if ((threadIdx.x & 63) == 0) atomicAdd(acc, (double)local);
}

__global__ void finalize(const double* __restrict__ acc, float* __restrict__ out) {
    out[0] = (float)(acc[0] * (1.0 / (double)HW));   // sum of per-image means
}

// ---------------------------------------------------------------- launch ----
extern "C" void kernel_launch(void* const* d_in, const int* in_sizes, int n_in,
                              void* d_out, int out_size, void* d_ws, size_t ws_size,
                              hipStream_t stream) {
    const float* x    = (const float*)d_in[0];
    const float* y    = (const float*)d_in[1];
    const float* mask = (const float*)d_in[2];
    float* out = (float*)d_out;

    // workspace layout
    char* ws = (char*)d_ws;
    float* bufA = (float*)(ws);                                  // 64 MB: vblur tmp, later mag
    float* bufB = (float*)(ws + (size_t)64 * 1024 * 1024);       // 64 MB: smoothed
    unsigned char* bin = (unsigned char*)(ws + (size_t)128 * 1024 * 1024);        // 16 MB
    unsigned long long* strongw = (unsigned long long*)(ws + (size_t)144 * 1024 * 1024); // 2 MB
    unsigned long long* weakw   = (unsigned long long*)(ws + (size_t)146 * 1024 * 1024); // 2 MB
    double* acc = (double*)(ws + (size_t)148 * 1024 * 1024);

    // gaussian taps (double, matching numpy f64 -> f32 cast)
    GW g;
    {
        double e[9], s = 0.0;
        for (int k = 0; k < 9; ++k) e[k] = std::exp(-0.5 * (k / 2.0) * (k / 2.0));
        s = e[0];
        for (int k = 1; k < 9; ++k) s += 2.0 * e[k];
        for (int k = 0; k < 9; ++k) g.w[k] = (float)(e[k] / s);
    }

    const int nblk = NHW / 256;   // 65536
    zero_acc<<<1, 1, 0, stream>>>(acc);
    blur_v  <<<nblk, 256, 0, stream>>>(x, bufA, g);
    blur_h  <<<nblk, 256, 0, stream>>>(bufA, bufB, g);
    grad_mag<<<nblk, 256, 0, stream>>>(bufB, bufA, bin);          // bufA now = mag
    nms_pack<<<nblk, 256, 0, stream>>>(bufA, bin, strongw, weakw);
    hyst    <<<NIMG, 1024, 0, stream>>>(strongw, weakw);
    loss_k  <<<2048, 256, 0, stream>>>(strongw, y, mask, acc);
    finalize<<<1, 1, 0, stream>>>(acc, out);
}

// Round 2
// 354.455 us; speedup vs baseline: 1.5817x; 1.5817x over previous
//
#include <hip/hip_runtime.h>
#include <cmath>

// Geometry fixed by reference: x,y (16,1,1024,1024) f32, mask (1024,1024) f32, out 1 f32
#define IMG_W   1024
#define IMG_H   1024
#define NIMG    16
#define HW      (1024 * 1024)
#define NHW     (16 * 1024 * 1024)
#define WPR     16                     // 64-bit words per row
#define WPI     (IMG_H * WPR)          // words per image

struct GW { float w[9]; };             // gaussian taps, w[|d|], d in [-8,8]

__device__ __forceinline__ int refl(int v) {        // reflect-101 for 1024
    return v < 0 ? -v : (v > 1023 ? 2046 - v : v);
}

// ------------------------------------------------- vertical blur (x -> vb) ----
// Each thread: one float4 column group, 8 consecutive output rows, register acc.
__global__ void blur_v(const float* __restrict__ in, float* __restrict__ out, GW g) {
    int gid = blockIdx.x * 256 + threadIdx.x;       // 16 img * 128 chunks * 256 colgroups
    int c4  = gid & 255;
    int rc  = (gid >> 8) & 127;
    const float* img = in  + (size_t)(gid >> 15) * HW;
    float*      outp = out + (size_t)(gid >> 15) * HW;
    int y0 = rc * 8;
    float4 acc[8];
#pragma unroll
    for (int j = 0; j < 8; ++j) acc[j] = make_float4(0.f, 0.f, 0.f, 0.f);
#pragma unroll
    for (int d = -8; d <= 15; ++d) {                // input rows y0+d
        int rr = refl(y0 + d);
        float4 v = *(const float4*)(img + rr * IMG_W + c4 * 4);
#pragma unroll
        for (int j = 0; j < 8; ++j) {
            int k = d - j;                           // tap offset, static after unroll
            if (k >= -8 && k <= 8) {
                float wt = g.w[k < 0 ? -k : k];
                acc[j].x += wt * v.x; acc[j].y += wt * v.y;
                acc[j].z += wt * v.z; acc[j].w += wt * v.w;
            }
        }
    }
#pragma unroll
    for (int j = 0; j < 8; ++j)
        *(float4*)(outp + (y0 + j) * IMG_W + c4 * 4) = acc[j];
}

// ---------------------- fused: horizontal blur + sobel + NMS + thresholds ----
// One block per 64x64 output tile. LDS holds (all at reflected global coords):
//   VB[l][m'] = vb(refl(r0+l-2), refl(c0+m'-10))      68 x 84
//   S [l][n]  = sm(refl(r0+l-2), refl(c0+n-2))        68 x 72 (68 cols used)
//   M (overlays VB): mag at tile-local (-1..64)^2, 0 outside image   66 x 68
//   Bn (after M): direction bin for the 64x64 centers
__global__ void __launch_bounds__(256)
hgradnms(const float* __restrict__ vb, unsigned long long* __restrict__ strongw,
         unsigned long long* __restrict__ weakw, GW g) {
    __shared__ float smem[68 * 84 + 68 * 72];       // 42432 B
    float* VB = smem;
    float* S  = smem + 68 * 84;
    float* M  = smem;                                // overlays VB (safe: phase3 reads only S)
    unsigned char* Bn = (unsigned char*)(smem + 66 * 68);

    int tid = threadIdx.x;
    int b   = blockIdx.x;
    int img = b >> 8;
    int tr  = (b >> 4) & 15, tc = b & 15;
    int r0  = tr * 64, c0 = tc * 64;
    const float* vimg = vb + (size_t)img * HW;

    // phase 1: gather vb tile (reflected coords)
    for (int i = tid; i < 68 * 84; i += 256) {
        int l = i / 84, m = i % 84;
        int gr = refl(r0 + l - 2);
        int gc = refl(c0 + m - 10);
        VB[i] = vimg[gr * IMG_W + gc];
    }
    __syncthreads();

    // phase 2: horizontal 17-tap blur, 4 outputs/item
    for (int i = tid; i < 68 * 17; i += 256) {
        int l = i / 17, grp = i % 17;
        const float4* p = (const float4*)(VB + l * 84 + 4 * grp);
        float w20[20];
        ((float4*)w20)[0] = p[0]; ((float4*)w20)[1] = p[1]; ((float4*)w20)[2] = p[2];
        ((float4*)w20)[3] = p[3]; ((float4*)w20)[4] = p[4];
        float o[4] = {0.f, 0.f, 0.f, 0.f};
#pragma unroll
        for (int t = 0; t < 17; ++t) {
            float wt = g.w[t < 8 ? 8 - t : t - 8];
#pragma unroll
            for (int j = 0; j < 4; ++j) o[j] += wt * w20[j + t];
        }
        *(float4*)(S + l * 72 + 4 * grp) = make_float4(o[0], o[1], o[2], o[3]);
    }
    __syncthreads();

    // phase 3: sobel -> mag (zero outside image) + bin for centers
    const float T1 = 0.41421356237309503f;   // tan(22.5)
    const float T2 = 2.41421356237309510f;   // tan(67.5)
    for (int i = tid; i < 66 * 17; i += 256) {
        int row = i / 17, grp = i % 17;      // M row 0..65 (= qr -1..64)
        float ra[8], rb[8], rcw[8];
        ((float4*)ra)[0]  = *(const float4*)(S + (row    ) * 72 + 4 * grp);
        ((float4*)ra)[1]  = *(const float4*)(S + (row    ) * 72 + 4 * grp + 4);
        ((float4*)rb)[0]  = *(const float4*)(S + (row + 1) * 72 + 4 * grp);
        ((float4*)rb)[1]  = *(const float4*)(S + (row + 1) * 72 + 4 * grp + 4);
        ((float4*)rcw)[0] = *(const float4*)(S + (row + 2) * 72 + 4 * grp);
        ((float4*)rcw)[1] = *(const float4*)(S + (row + 2) * 72 + 4 * grp + 4);
        int pr = r0 + row - 1;
        bool rin = (unsigned)pr <= 1023u;
#pragma unroll
        for (int j = 0; j < 4; ++j) {
            int colidx = 4 * grp + j;        // 0..67; valid M cols 0..65
            if (colidx > 65) continue;
            int pc = c0 + colidx - 1;
            bool in = rin && ((unsigned)pc <= 1023u);
            float a00 = ra[j], a01 = ra[j + 1], a02 = ra[j + 2];
            float a10 = rb[j],                  a12 = rb[j + 2];
            float a20 = rcw[j], a21 = rcw[j + 1], a22 = rcw[j + 2];
            float gx = (a02 - a00) + 2.f * (a12 - a10) + (a22 - a20);
            float gy = (a20 + 2.f * a21 + a22) - (a00 + 2.f * a01 + a02);
            float mv = in ? sqrtf(gx * gx + gy * gy) : 0.f;
            M[row * 68 + colidx] = mv;
            if (row >= 1 && row <= 64 && colidx >= 1 && colidx <= 64) {
                float ax = fabsf(gx), ay = fabsf(gy);
                int bn;
                if (ay < T1 * ax)      bn = 0;
                else if (ay > T2 * ax) bn = 2;
                else                   bn = ((gx > 0.f) == (gy > 0.f)) ? 1 : 3;
                Bn[(row - 1) * 64 + (colidx - 1)] = (unsigned char)bn;
            }
        }
    }
    __syncthreads();

    // phase 4: NMS + thresholds + ballot pack
    int lane = tid & 63, wv = tid >> 6;
    unsigned long long* sgw = strongw + (size_t)img * WPI;
    unsigned long long* wkw = weakw   + (size_t)img * WPI;
    for (int it = 0; it < 16; ++it) {
        int qr = wv * 16 + it;
        int qc = lane;
        float cm = M[(qr + 1) * 68 + qc + 1];
        int bn = Bn[qr * 64 + qc];
        int d1y = (bn == 0) ? 0 : -1;
        int d1x = (bn < 2) ? 1 : ((bn == 2) ? 0 : -1);
        float n1 = M[(qr + 1 + d1y) * 68 + (qc + 1 + d1x)];
        float n2 = M[(qr + 1 - d1y) * 68 + (qc + 1 - d1x)];
        bool keep   = (cm >= n1) && (cm >= n2);
        bool strong = keep && (cm > 0.2f);
        bool weak   = keep && (cm > 0.1f);
        unsigned long long sb = __ballot(strong);
        unsigned long long wb = __ballot(weak);
        if (lane == 0) {
            int widx = (r0 + qr) * WPR + tc;
            sgw[widx] = sb;
            wkw[widx] = wb;
        }
    }
}

// ------------------------------------------------------------ hysteresis ----
// One workgroup per image; strong bits in 128KB LDS; zigzag Gauss-Seidel
// sweeps to the same fixpoint as the reference while_loop. Weak words
// cached in registers (static indexing only).
__global__ void __launch_bounds__(1024, 1)
hyst(unsigned long long* __restrict__ strongw, const unsigned long long* __restrict__ weakw) {
    __shared__ unsigned long long S[WPI];
    __shared__ int chg;
    unsigned long long* sg = strongw + (size_t)blockIdx.x * WPI;
    const unsigned long long* wk = weakw + (size_t)blockIdx.x * WPI;
    int t = threadIdx.x;
    int c = t & 15;
    int rbase = (t >> 4) * 16;

    unsigned long long ww[16];
#pragma unroll
    for (int i = 0; i < 16; ++i) {
        S[(rbase + i) * WPR + c] = sg[(rbase + i) * WPR + c];
        ww[i] = wk[(rbase + i) * WPR + c];
    }
    __syncthreads();

    for (int pass = 0; pass < 4096; ++pass) {
        if (t == 0) chg = 0;
        __syncthreads();
        int any = 0;
        auto step = [&](int r, unsigned long long wwv) {
            unsigned long long w = S[r * WPR + c];
            if (!(wwv & ~w)) return;
            unsigned long long up = 0, dn = 0, upl = 0, upr = 0, dnl = 0, dnr = 0, ml = 0, mr = 0;
            if (r > 0)    { up = S[(r - 1) * WPR + c];
                            if (c > 0)  upl = S[(r - 1) * WPR + c - 1];
                            if (c < 15) upr = S[(r - 1) * WPR + c + 1]; }
            if (r < 1023) { dn = S[(r + 1) * WPR + c];
                            if (c > 0)  dnl = S[(r + 1) * WPR + c - 1];
                            if (c < 15) dnr = S[(r + 1) * WPR + c + 1]; }
            if (c > 0)  ml = S[r * WPR + c - 1];
            if (c < 15) mr = S[r * WPR + c + 1];
            unsigned long long H =
                  up | (up << 1) | (up >> 1) | (upl >> 63) | (upr << 63)
                | w  | (w  << 1) | (w  >> 1) | (ml  >> 63) | (mr  << 63)
                | dn | (dn << 1) | (dn >> 1) | (dnl >> 63) | (dnr << 63);
            unsigned long long nw = w | (H & wwv);
            for (;;) {
                unsigned long long nn = nw | (((nw << 1) | (nw >> 1)) & wwv);
                if (nn == nw) break;
                nw = nn;
            }
            if (nw != w) { S[r * WPR + c] = nw; any = 1; }
        };
        if (!(pass & 1)) {
#pragma unroll
            for (int i = 0; i < 16; ++i) step(rbase + i, ww[i]);
        } else {
#pragma unroll
            for (int i = 15; i >= 0; --i) step(rbase + i, ww[i]);
        }
        if (any) chg = 1;
        __syncthreads();
        int done = (chg == 0);
        __syncthreads();
        if (done) break;
    }
#pragma unroll
    for (int i = 0; i < 16; ++i) sg[(rbase + i) * WPR + c] = S[(rbase + i) * WPR + c];
}

// ------------------------------------------------------------------ loss ----
__global__ void loss_part(const unsigned long long* __restrict__ strongw,
                          const float* __restrict__ y, const float* __restrict__ mask,
                          float* __restrict__ part) {
    int tid = threadIdx.x;
    float local = 0.f;
    const float4* y4 = (const float4*)y;
    const float4* m4 = (const float4*)mask;
    for (int i4 = blockIdx.x * 256 + tid; i4 < NHW / 4; i4 += 2048 * 256) {
        unsigned long long wword = strongw[i4 >> 4];
        int sh = (i4 & 15) * 4;
        unsigned bits = (unsigned)((wword >> sh) & 0xFull);
        float4 yv = y4[i4];
        float4 mv = m4[i4 & (HW / 4 - 1)];
        // exact per-element ops of reference: |e*m - y*m|
        local += fabsf(((bits & 1u) ? mv.x : 0.f) - yv.x * mv.x);
        local += fabsf(((bits & 2u) ? mv.y : 0.f) - yv.y * mv.y);
        local += fabsf(((bits & 4u) ? mv.z : 0.f) - yv.z * mv.z);
        local += fabsf(((bits & 8u) ? mv.w : 0.f) - yv.w * mv.w);
    }
    for (int off = 32; off; off >>= 1) local += __shfl_down(local, off);
    __shared__ float wsum[4];
    if ((tid & 63) == 0) wsum[tid >> 6] = local;
    __syncthreads();
    if (tid == 0) part[blockIdx.x] = wsum[0] + wsum[1] + wsum[2] + wsum[3];
}

__global__ void loss_final(const float* __restrict__ part, float* __restrict__ out) {
    int tid = threadIdx.x;
    double s = 0.0;
    for (int i = tid; i < 2048; i += 256) s += (double)part[i];
    for (int off = 32; off; off >>= 1) s += __shfl_down(s, off);
    __shared__ double ws4[4];
    if ((tid & 63) == 0) ws4[tid >> 6] = s;
    __syncthreads();
    if (tid == 0) out[0] = (float)((ws4[0] + ws4[1] + ws4[2] + ws4[3]) * (1.0 / (double)HW));
}

// ---------------------------------------------------------------- launch ----
extern "C" void kernel_launch(void* const* d_in, const int* in_sizes, int n_in,
                              void* d_out, int out_size, void* d_ws, size_t ws_size,
                              hipStream_t stream) {
    const float* x    = (const float*)d_in[0];
    const float* y    = (const float*)d_in[1];
    const float* mask = (const float*)d_in[2];
    float* out = (float*)d_out;

    char* ws = (char*)d_ws;
    float* vbuf = (float*)(ws);                                              // 64 MB
    unsigned long long* strongw = (unsigned long long*)(ws + (size_t)64 * 1024 * 1024); // 2 MB
    unsigned long long* weakw   = (unsigned long long*)(ws + (size_t)66 * 1024 * 1024); // 2 MB
    float* part = (float*)(ws + (size_t)68 * 1024 * 1024);                   // 8 KB

    GW g;
    {
        double e[9], s;
        for (int k = 0; k < 9; ++k) e[k] = std::exp(-0.5 * (k / 2.0) * (k / 2.0));
        s = e[0];
        for (int k = 1; k < 9; ++k) s += 2.0 * e[k];
        for (int k = 0; k < 9; ++k) g.w[k] = (float)(e[k] / s);
    }

    blur_v    <<<2048, 256, 0, stream>>>(x, vbuf, g);
    hgradnms  <<<4096, 256, 0, stream>>>(vbuf, strongw, weakw, g);
    hyst      <<<NIMG, 1024, 0, stream>>>(strongw, weakw);
    loss_part <<<2048, 256, 0, stream>>>(strongw, y, mask, part);
    loss_final<<<1, 256, 0, stream>>>(part, out);
}

// Round 7
// 339.423 us; speedup vs baseline: 1.6517x; 1.0443x over previous
//
#include <hip/hip_runtime.h>
#include <cmath>

// Geometry fixed by reference: x,y (16,1,1024,1024) f32, mask (1024,1024) f32, out 1 f32
#define IMG_W   1024
#define IMG_H   1024
#define NIMG    16
#define HW      (1024 * 1024)
#define NHW     (16 * 1024 * 1024)
#define WPR     16                     // 64-bit words per row
#define WPI     (IMG_H * WPR)          // words per image

struct GW { float w[9]; };             // gaussian taps, w[|d|], d in [-8,8]

__device__ __forceinline__ int refl(int v) {        // reflect-101 for 1024
    return v < 0 ? -v : (v > 1023 ? 2046 - v : v);
}

// ------------------------------------------------- vertical blur (x -> vb) ----
__global__ void blur_v(const float* __restrict__ in, float* __restrict__ out, GW g) {
    int gid = blockIdx.x * 256 + threadIdx.x;
    int c4  = gid & 255;
    int rc  = (gid >> 8) & 127;
    const float* img = in  + (size_t)(gid >> 15) * HW;
    float*      outp = out + (size_t)(gid >> 15) * HW;
    int y0 = rc * 8;
    float4 acc[8];
#pragma unroll
    for (int j = 0; j < 8; ++j) acc[j] = make_float4(0.f, 0.f, 0.f, 0.f);
#pragma unroll
    for (int d = -8; d <= 15; ++d) {
        int rr = refl(y0 + d);
        float4 v = *(const float4*)(img + rr * IMG_W + c4 * 4);
#pragma unroll
        for (int j = 0; j < 8; ++j) {
            int k = d - j;
            if (k >= -8 && k <= 8) {
                float wt = g.w[k < 0 ? -k : k];
                acc[j].x += wt * v.x; acc[j].y += wt * v.y;
                acc[j].z += wt * v.z; acc[j].w += wt * v.w;
            }
        }
    }
#pragma unroll
    for (int j = 0; j < 8; ++j)
        *(float4*)(outp + (y0 + j) * IMG_W + c4 * 4) = acc[j];
}

// ---------------------- fused: horizontal blur + sobel + NMS + thresholds ----
// One block per 64x64 output tile. Single LDS buffer L (68 x 88 floats, 23.9KB),
// reused in-place across phases (all writes are regs->barrier->store):
//   phase1: L[l][m] = vb(refl(r0+l-2), c0-12+m)      l=0..67, m=0..87
//   phase2: L[l][n] = sm at (refl(r0+l-2), c0+n-2)   n=0..67 (in-place, cols 68..87 stale)
//   phase3: M[row][col] (stride 68, rows 0..65 = img rows r0-1..r0+64, 0 outside img)
//           Bn bytes at L+4488 floats (stride 68)
//   phase4: NMS + thresholds + ballot pack
__global__ void __launch_bounds__(256, 5)
hgradnms(const float* __restrict__ vb, unsigned long long* __restrict__ strongw,
         unsigned long long* __restrict__ weakw, GW g) {
    __shared__ float L[68 * 88];                     // 23936 B
    unsigned char* Bn = (unsigned char*)(L + 66 * 68);   // 4488 bytes

    int tid = threadIdx.x;
    int b   = blockIdx.x;
    int img = b >> 8;
    int tr  = (b >> 4) & 15, tc = b & 15;
    int r0  = tr * 64, c0 = tc * 64;
    const float* vimg = vb + (size_t)img * HW;

    // ---- phase 1: gather vb tile ----
    if (tc > 0 && tc < 15) {
        // interior cols: c0-12 .. c0+75 all in-image, 16B aligned -> float4 loads
        const float* basep = vimg + (c0 - 12);
        for (int i = tid; i < 68 * 22; i += 256) {
            int l = i / 22, q = i % 22;
            int gr = refl(r0 + l - 2);
            *(float4*)(L + l * 88 + 4 * q) = *(const float4*)(basep + gr * IMG_W + 4 * q);
        }
    } else {
        for (int i = tid; i < 68 * 88; i += 256) {
            int l = i / 88, m = i % 88;
            int gr = refl(r0 + l - 2);
            int gc = refl(c0 - 12 + m);
            L[i] = vimg[gr * IMG_W + gc];
        }
    }
    __syncthreads();

    // ---- phase 2: horizontal 17-tap blur (regs -> barrier -> in-place) ----
    float4 oreg[5];
#pragma unroll
    for (int it = 0; it < 5; ++it) {
        int i = tid + it * 256;
        if (i < 68 * 17) {
            int l = i / 17, gq = i % 17;
            float w24[24];
#pragma unroll
            for (int q = 0; q < 6; ++q)
                ((float4*)w24)[q] = *(const float4*)(L + l * 88 + 4 * gq + 4 * q);
            float o0 = 0.f, o1 = 0.f, o2 = 0.f, o3 = 0.f;
#pragma unroll
            for (int t = 0; t < 17; ++t) {
                float wt = g.w[t < 8 ? 8 - t : t - 8];
                o0 += wt * w24[2 + t]; o1 += wt * w24[3 + t];
                o2 += wt * w24[4 + t]; o3 += wt * w24[5 + t];
            }
            oreg[it] = make_float4(o0, o1, o2, o3);
        }
    }
    __syncthreads();
#pragma unroll
    for (int it = 0; it < 5; ++it) {
        int i = tid + it * 256;
        if (i < 68 * 17) {
            int l = i / 17, gq = i % 17;
            *(float4*)(L + l * 88 + 4 * gq) = oreg[it];
        }
    }
    __syncthreads();

    // ---- phase 3: sobel -> mag + bin (regs -> barrier -> overlay M, Bn) ----
    const float T1 = 0.41421356237309503f;   // tan(22.5)
    const float T2 = 2.41421356237309510f;   // tan(67.5)
    float4 mreg[5];
    unsigned int breg[5];
#pragma unroll
    for (int it = 0; it < 5; ++it) {
        int i = tid + it * 256;
        if (i < 66 * 17) {
            int row = i / 17, gq = i % 17;
            float ra[8], rb[8], rc8[8];
            ((float4*)ra)[0]  = *(const float4*)(L + (row    ) * 88 + 4 * gq);
            ((float4*)ra)[1]  = *(const float4*)(L + (row    ) * 88 + 4 * gq + 4);
            ((float4*)rb)[0]  = *(const float4*)(L + (row + 1) * 88 + 4 * gq);
            ((float4*)rb)[1]  = *(const float4*)(L + (row + 1) * 88 + 4 * gq + 4);
            ((float4*)rc8)[0] = *(const float4*)(L + (row + 2) * 88 + 4 * gq);
            ((float4*)rc8)[1] = *(const float4*)(L + (row + 2) * 88 + 4 * gq + 4);
            int pr = r0 + row - 1;
            bool rin = (unsigned)pr <= 1023u;
            float mv[4]; unsigned int bpk = 0;
#pragma unroll
            for (int j = 0; j < 4; ++j) {
                int colidx = 4 * gq + j;
                float a00 = ra[j], a01 = ra[j + 1], a02 = ra[j + 2];
                float a10 = rb[j],                   a12 = rb[j + 2];
                float a20 = rc8[j], a21 = rc8[j + 1], a22 = rc8[j + 2];
                float gx = (a02 - a00) + 2.f * (a12 - a10) + (a22 - a20);
                float gy = (a20 + 2.f * a21 + a22) - (a00 + 2.f * a01 + a02);
                int pc = c0 + colidx - 1;
                bool in = rin && ((unsigned)pc <= 1023u) && (colidx <= 65);
                mv[j] = in ? sqrtf(gx * gx + gy * gy) : 0.f;
                float ax = fabsf(gx), ay = fabsf(gy);
                int bn;
                if (ay < T1 * ax)      bn = 0;
                else if (ay > T2 * ax) bn = 2;
                else                   bn = ((gx > 0.f) == (gy > 0.f)) ? 1 : 3;
                bpk |= (unsigned)bn << (8 * j);
            }
            mreg[it] = make_float4(mv[0], mv[1], mv[2], mv[3]);
            breg[it] = bpk;
        }
    }
    __syncthreads();
#pragma unroll
    for (int it = 0; it < 5; ++it) {
        int i = tid + it * 256;
        if (i < 66 * 17) {
            int row = i / 17, gq = i % 17;
            *(float4*)(L + row * 68 + 4 * gq) = mreg[it];          // M, stride 68
            *(unsigned int*)(Bn + row * 68 + 4 * gq) = breg[it];   // bins
        }
    }
    __syncthreads();

    // ---- phase 4: NMS + thresholds + ballot pack ----
    int lane = tid & 63, wv = tid >> 6;
    unsigned long long* sgw = strongw + (size_t)img * WPI;
    unsigned long long* wkw = weakw   + (size_t)img * WPI;
    for (int it = 0; it < 16; ++it) {
        int qr = wv * 16 + it;
        int qc = lane;
        float cm = L[(qr + 1) * 68 + qc + 1];
        int bn = Bn[(qr + 1) * 68 + qc + 1];
        int d1y = (bn == 0) ? 0 : -1;
        int d1x = (bn < 2) ? 1 : ((bn == 2) ? 0 : -1);
        float n1 = L[(qr + 1 + d1y) * 68 + (qc + 1 + d1x)];
        float n2 = L[(qr + 1 - d1y) * 68 + (qc + 1 - d1x)];
        bool keep   = (cm >= n1) && (cm >= n2);
        bool strong = keep && (cm > 0.2f);
        bool weak   = keep && (cm > 0.1f);
        unsigned long long sb = __ballot(strong);
        unsigned long long wb = __ballot(weak);
        if (lane == 0) {
            int widx = (r0 + qr) * WPR + tc;
            sgw[widx] = sb;
            wkw[widx] = wb;
        }
    }
}

// ------------------------------------------------------------ hysteresis ----
__global__ void __launch_bounds__(1024, 1)
hyst(unsigned long long* __restrict__ strongw, const unsigned long long* __restrict__ weakw) {
    __shared__ unsigned long long S[WPI];
    __shared__ int chg;
    unsigned long long* sg = strongw + (size_t)blockIdx.x * WPI;
    const unsigned long long* wk = weakw + (size_t)blockIdx.x * WPI;
    int t = threadIdx.x;
    int c = t & 15;
    int rbase = (t >> 4) * 16;

    unsigned long long ww[16];
#pragma unroll
    for (int i = 0; i < 16; ++i) {
        S[(rbase + i) * WPR + c] = sg[(rbase + i) * WPR + c];
        ww[i] = wk[(rbase + i) * WPR + c];
    }
    __syncthreads();

    for (int pass = 0; pass < 4096; ++pass) {
        if (t == 0) chg = 0;
        __syncthreads();
        int any = 0;
        auto step = [&](int r, unsigned long long wwv) {
            unsigned long long w = S[r * WPR + c];
            if (!(wwv & ~w)) return;
            unsigned long long up = 0, dn = 0, upl = 0, upr = 0, dnl = 0, dnr = 0, ml = 0, mr = 0;
            if (r > 0)    { up = S[(r - 1) * WPR + c];
                            if (c > 0)  upl = S[(r - 1) * WPR + c - 1];
                            if (c < 15) upr = S[(r - 1) * WPR + c + 1]; }
            if (r < 1023) { dn = S[(r + 1) * WPR + c];
                            if (c > 0)  dnl = S[(r + 1) * WPR + c - 1];
                            if (c < 15) dnr = S[(r + 1) * WPR + c + 1]; }
            if (c > 0)  ml = S[r * WPR + c - 1];
            if (c < 15) mr = S[r * WPR + c + 1];
            unsigned long long H =
                  up | (up << 1) | (up >> 1) | (upl >> 63) | (upr << 63)
                | w  | (w  << 1) | (w  >> 1) | (ml  >> 63) | (mr  << 63)
                | dn | (dn << 1) | (dn >> 1) | (dnl >> 63) | (dnr << 63);
            unsigned long long nw = w | (H & wwv);
            for (;;) {
                unsigned long long nn = nw | (((nw << 1) | (nw >> 1)) & wwv);
                if (nn == nw) break;
                nw = nn;
            }
            if (nw != w) { S[r * WPR + c] = nw; any = 1; }
        };
        if (!(pass & 1)) {
#pragma unroll
            for (int i = 0; i < 16; ++i) step(rbase + i, ww[i]);
        } else {
#pragma unroll
            for (int i = 15; i >= 0; --i) step(rbase + i, ww[i]);
        }
        if (any) chg = 1;
        __syncthreads();
        int done = (chg == 0);
        __syncthreads();
        if (done) break;
    }
#pragma unroll
    for (int i = 0; i < 16; ++i) sg[(rbase + i) * WPR + c] = S[(rbase + i) * WPR + c];
}

// ------------------------------------------------------------------ loss ----
__global__ void loss_part(const unsigned long long* __restrict__ strongw,
                          const float* __restrict__ y, const float* __restrict__ mask,
                          float* __restrict__ part) {
    int tid = threadIdx.x;
    float local = 0.f;
    const float4* y4 = (const float4*)y;
    const float4* m4 = (const float4*)mask;
    for (int i4 = blockIdx.x * 256 + tid; i4 < NHW / 4; i4 += 2048 * 256) {
        unsigned long long wword = strongw[i4 >> 4];
        int sh = (i4 & 15) * 4;
        unsigned bits = (unsigned)((wword >> sh) & 0xFull);
        float4 yv = y4[i4];
        float4 mv = m4[i4 & (HW / 4 - 1)];
        local += fabsf(((bits & 1u) ? mv.x : 0.f) - yv.x * mv.x);
        local += fabsf(((bits & 2u) ? mv.y : 0.f) - yv.y * mv.y);
        local += fabsf(((bits & 4u) ? mv.z : 0.f) - yv.z * mv.z);
        local += fabsf(((bits & 8u) ? mv.w : 0.f) - yv.w * mv.w);
    }
    for (int off = 32; off; off >>= 1) local += __shfl_down(local, off);
    __shared__ float wsum[4];
    if ((tid & 63) == 0) wsum[tid >> 6] = local;
    __syncthreads();
    if (tid == 0) part[blockIdx.x] = wsum[0] + wsum[1] + wsum[2] + wsum[3];
}

__global__ void loss_final(const float* __restrict__ part, float* __restrict__ out) {
    int tid = threadIdx.x;
    double s = 0.0;
    for (int i = tid; i < 2048; i += 256) s += (double)part[i];
    for (int off = 32; off; off >>= 1) s += __shfl_down(s, off);
    __shared__ double ws4[4];
    if ((tid & 63) == 0) ws4[tid >> 6] = s;
    __syncthreads();
    if (tid == 0) out[0] = (float)((ws4[0] + ws4[1] + ws4[2] + ws4[3]) * (1.0 / (double)HW));
}

// ---------------------------------------------------------------- launch ----
extern "C" void kernel_launch(void* const* d_in, const int* in_sizes, int n_in,
                              void* d_out, int out_size, void* d_ws, size_t ws_size,
                              hipStream_t stream) {
    const float* x    = (const float*)d_in[0];
    const float* y    = (const float*)d_in[1];
    const float* mask = (const float*)d_in[2];
    float* out = (float*)d_out;

    char* ws = (char*)d_ws;
    float* vbuf = (float*)(ws);                                              // 64 MB
    unsigned long long* strongw = (unsigned long long*)(ws + (size_t)64 * 1024 * 1024); // 2 MB
    unsigned long long* weakw   = (unsigned long long*)(ws + (size_t)66 * 1024 * 1024); // 2 MB
    float* part = (float*)(ws + (size_t)68 * 1024 * 1024);                   // 8 KB

    GW g;
    {
        double e[9], s;
        for (int k = 0; k < 9; ++k) e[k] = std::exp(-0.5 * (k / 2.0) * (k / 2.0));
        s = e[0];
        for (int k = 1; k < 9; ++k) s += 2.0 * e[k];
        for (int k = 0; k < 9; ++k) g.w[k] = (float)(e[k] / s);
    }

    blur_v    <<<2048, 256, 0, stream>>>(x, vbuf, g);
    hgradnms  <<<4096, 256, 0, stream>>>(vbuf, strongw, weakw, g);
    hyst      <<<NIMG, 1024, 0, stream>>>(strongw, weakw);
    loss_part <<<2048, 256, 0, stream>>>(strongw, y, mask, part);
    loss_final<<<1, 256, 0, stream>>>(part, out);
}